// Round 6
// baseline (190.679 us; speedup 1.0000x reference)
//
#include <hip/hip_runtime.h>
#include <math.h>

#define N_TOK 4096
#define C_DIM 256
#define G_DIM 31
#define E_DIM 32
#define H_DIM 1024
#define TT    16   // fp32 fallback tile
#define MT    32   // mfma tile tokens
#define TBL_MAX 576

typedef unsigned short ushort_t;
typedef unsigned int uint_t;
typedef __attribute__((ext_vector_type(8))) short bfrag;
typedef __attribute__((ext_vector_type(4))) float f32x4;
typedef __attribute__((ext_vector_type(8))) unsigned short ushort8;

__device__ __forceinline__ ushort_t f2bf(float f) {
    uint_t u = __float_as_uint(f);
    uint_t r = (u + 0x7fffu + ((u >> 16) & 1u)) >> 16;
    return (ushort_t)r;
}

__device__ __forceinline__ float gelu_f(float v) {
    float u = 0.7978845608f * fmaf(0.044715f * v * v, v, v);
    float t = __expf(-2.f * u);
    return 0.5f * v * (1.f + (1.f - t) / (1.f + t));
}

// ---------------- prep kernel ----------------
// blocks [0, nfc): Wfc transform (LDS transpose, coalesced)
// blocks [nfc, nwt): Wproj transform
// blocks [nwt, nwt+1024): gate (wave per token)
//
// WfcF  frag block id = e*512 + kt*64 + nt   (kt: K=C 8x32, nt: N=H 64x16)
// WprojF frag block id = e*512 + kt*16 + nt  (kt: K=H 32x32, nt: N=C 16x16)
// Within block: lane's 8 bf16 = B[k0+(lane>>4)*8+j][n0+(lane&15)]
// btok packed: tok | (slot << 12), slot 0..3 (0 = shared expert)
__global__ __launch_bounds__(256) void prep_kernel(
    const float* __restrict__ Wfc, const float* __restrict__ Wproj,
    ushort_t* __restrict__ WfcF, ushort_t* __restrict__ WprojF,
    const float* __restrict__ xf, const float* __restrict__ rfp,
    const float* __restrict__ Wg, const float* __restrict__ bg,
    const float* __restrict__ ebias,
    float* __restrict__ rw_out, int* __restrict__ counts,
    int* __restrict__ btok, float* __restrict__ bwgt,
    float* __restrict__ ref2_out, int nfc, int nwt)
{
    __shared__ __align__(16) char sraw[32 * 516 * 2];   // 33024 B, aliased per path
    const int tid = threadIdx.x;

    if ((int)blockIdx.x < nfc) {
        // ---- Wfc: block = (e, kt, half); tile = rows kt*32..+31 (c), cols half*512..+511 (h) ----
        const int b = blockIdx.x;
        const int e = b >> 4, kt = (b >> 1) & 7, half = b & 1;
        const float* src = Wfc + ((size_t)e << 18) + (size_t)(kt * 32) * H_DIM + half * 512;
        ushort_t (*s)[516] = (ushort_t(*)[516])sraw;
        #pragma unroll
        for (int i = 0; i < 16; ++i) {
            int flat = i * 256 + tid;            // 0..4095 float4 slots
            int r = flat >> 7, q = flat & 127;   // 128 float4 per row
            float4 v = *(const float4*)(src + (size_t)r * H_DIM + q * 4);
            s[r][q * 4 + 0] = f2bf(v.x);
            s[r][q * 4 + 1] = f2bf(v.y);
            s[r][q * 4 + 2] = f2bf(v.z);
            s[r][q * 4 + 3] = f2bf(v.w);
        }
        __syncthreads();
        const int l = tid & 63, w = tid >> 6;
        #pragma unroll
        for (int t = 0; t < 8; ++t) {
            int ntl = w + t * 4;                 // 0..31 within half
            ushort8 pv;
            #pragma unroll
            for (int j = 0; j < 8; ++j)
                pv[j] = s[(l >> 4) * 8 + j][ntl * 16 + (l & 15)];
            int fb = e * 512 + kt * 64 + half * 32 + ntl;
            *(ushort8*)(WfcF + ((size_t)fb * 64 + l) * 8) = pv;
        }
        return;
    }

    if ((int)blockIdx.x < nwt) {
        // ---- Wproj: block = (e, kt); tile = rows kt*32..+31 (h), all 256 cols (c) ----
        const int b2 = blockIdx.x - nfc;
        const int e = b2 >> 5, kt = b2 & 31;
        const float* src = Wproj + ((size_t)e << 18) + (size_t)(kt * 32) * C_DIM;
        ushort_t (*s)[260] = (ushort_t(*)[260])sraw;
        #pragma unroll
        for (int i = 0; i < 8; ++i) {
            int flat = i * 256 + tid;            // 0..2047 float4 slots
            int r = flat >> 6, q = flat & 63;    // 64 float4 per row
            float4 v = *(const float4*)(src + (size_t)r * C_DIM + q * 4);
            s[r][q * 4 + 0] = f2bf(v.x);
            s[r][q * 4 + 1] = f2bf(v.y);
            s[r][q * 4 + 2] = f2bf(v.z);
            s[r][q * 4 + 3] = f2bf(v.w);
        }
        __syncthreads();
        const int l = tid & 63, w = tid >> 6;
        #pragma unroll
        for (int t = 0; t < 4; ++t) {
            int nt = w + t * 4;                  // 0..15
            ushort8 pv;
            #pragma unroll
            for (int j = 0; j < 8; ++j)
                pv[j] = s[(l >> 4) * 8 + j][nt * 16 + (l & 15)];
            int fb = e * 512 + kt * 16 + nt;
            *(ushort8*)(WprojF + ((size_t)fb * 64 + l) * 8) = pv;
        }
        return;
    }

    // ---------------- gate: wave per token, 4 tokens/block ----------------
    const int b2 = blockIdx.x - nwt;
    const int w = tid >> 6, l = tid & 63;
    const int tok = b2 * 4 + w;
    float (*xs)[C_DIM] = (float(*)[C_DIM])sraw;

    if (b2 == 0 && tid == 0) counts[0] = N_TOK;  // shared expert: all tokens

    float4 xv = *(const float4*)(xf + (size_t)tok * C_DIM + l * 4);
    float4 rv = *(const float4*)(rfp + (size_t)tok * C_DIM + l * 4);
    *(float4*)(&xs[w][l * 4]) = xv;
    float r2 = rv.x * rv.x + rv.y * rv.y + rv.z * rv.z + rv.w * rv.w;
    #pragma unroll
    for (int off = 32; off; off >>= 1) r2 += __shfl_xor(r2, off);
    if (l == 0) ref2_out[tok] = r2;
    __syncthreads();

    const int g = l & 31, half = l >> 5;
    float acc = 0.f;
    if (g < G_DIM) {
        const float* xr = xs[w] + half * 128;
        const float* wg = Wg + (size_t)(half * 128) * G_DIM + g;
        #pragma unroll 4
        for (int c = 0; c < 128; ++c)
            acc = fmaf(xr[c], wg[(size_t)c * G_DIM], acc);
    }
    acc += __shfl_xor(acc, 32);
    float lg = acc + ((g < G_DIM) ? bg[g] : 0.f);

    float v = (l < G_DIM) ? lg : -1e30f;
    float m = v;
    #pragma unroll
    for (int off = 32; off; off >>= 1) m = fmaxf(m, __shfl_xor(m, off));
    float pex = (l < G_DIM) ? __expf(v - m) : 0.f;
    float s = pex;
    #pragma unroll
    for (int off = 32; off; off >>= 1) s += __shfl_xor(s, off);
    float p = (l < G_DIM) ? (pex / s + ebias[l]) : -1e30f;

    float w3[3]; int id3[3];
    float vv = p;
    #pragma unroll
    for (int t = 0; t < 3; ++t) {
        float bv = vv; int bi = l;
        #pragma unroll
        for (int off = 32; off; off >>= 1) {
            float ov = __shfl_xor(bv, off); int oi = __shfl_xor(bi, off);
            if (ov > bv || (ov == bv && oi < bi)) { bv = ov; bi = oi; }
        }
        w3[t] = bv; id3[t] = bi;
        if (l == bi) vv = -1e30f;
    }
    float vs = w3[0] + w3[1] + w3[2];
    #pragma unroll
    for (int t = 0; t < 3; ++t) w3[t] = (w3[t] / vs) * 0.75f;

    if (l < 32) {
        float r = (l == 0) ? 0.25f : 0.f;
        #pragma unroll
        for (int t = 0; t < 3; ++t) if (l == id3[t] + 1) r = w3[t];
        rw_out[(size_t)tok * E_DIM + l] = r;
    }

    if (l == 0) {
        btok[tok] = tok;          // expert 0, slot 0
        bwgt[tok] = 0.25f;
        #pragma unroll
        for (int t = 0; t < 3; ++t) {
            int e = id3[t] + 1;
            int slot = atomicAdd(&counts[e], 1);
            btok[(size_t)e * N_TOK + slot] = tok | ((t + 1) << 12);
            bwgt[(size_t)e * N_TOK + slot] = w3[t];
        }
    }
}

// ---------------- finalize: compact (expert,tile) table + total ----------------
// tbl[0] = total tiles; tbl[1+i] = e | (local_tile << 8)
__global__ __launch_bounds__(64) void finalize_kernel(
    const int* __restrict__ counts, int* __restrict__ tbl)
{
    const int l = threadIdx.x;
    int cnt = (l < E_DIM) ? counts[l] : 0;
    int tiles = (cnt + MT - 1) / MT;
    int x = tiles;
    #pragma unroll
    for (int off = 1; off < 64; off <<= 1) {
        int y = __shfl_up(x, off);
        if (l >= off) x += y;
    }
    int base = x - tiles;   // exclusive prefix
    if (l == 63) tbl[0] = x;
    if (l < E_DIM)
        for (int t = 0; t < tiles; ++t)
            tbl[1 + base + t] = l | (t << 8);
}

// ---------------- MFMA expert kernel: 32 tokens, depth-2 pipelined, compacted grid ----------------
__global__ __launch_bounds__(256, 2) void expert_mfma32p(
    const float* __restrict__ xf, const float* __restrict__ rfp,
    const ushort_t* __restrict__ WfcF, const ushort_t* __restrict__ WprojF,
    const float* __restrict__ bfc, const float* __restrict__ bproj,
    const float* __restrict__ cptr, const float* __restrict__ ref2p,
    const int* __restrict__ counts, const int* __restrict__ btok,
    const float* __restrict__ bwgt, const int* __restrict__ tbl,
    float* __restrict__ part)
{
    // inverse-XCD swizzle: consecutive table entries (same expert) -> same XCD
    const int T = (blockIdx.x & 7) * (TBL_MAX / 8) + (blockIdx.x >> 3);
    const int tot = tbl[0];
    if (T >= tot) return;
    const int ent = tbl[1 + T];
    const int e = ent & 0xFF;
    const int base = (ent >> 8) * MT;
    const int cnt = counts[e];
    const int ntk = min(MT, cnt - base);
    const int tid = threadIdx.x;
    const int lane = tid & 63;
    const int w = tid >> 6;

    __shared__ __align__(16) ushort_t hfrag[MT * H_DIM];  // 64 KB
    __shared__ int   spk[MT];
    __shared__ float swgt[MT];

    if (tid < MT) {
        bool vld = (base + tid) < cnt;
        spk[tid]  = btok[(size_t)e * N_TOK + (vld ? base + tid : base)];
        swgt[tid] = vld ? bwgt[(size_t)e * N_TOK + base + tid] : 0.f;
    }
    __syncthreads();

    // ---- stage x into phase-1 A-frag layout ----
    {
        const int r  = tid >> 3;
        const int c0 = (tid & 7) * 32;
        const int mt = r >> 4, rr = r & 15;
        const int kt = c0 >> 5;
        const bool valid = (r < ntk);
        const float* xrow = xf + (size_t)(spk[r] & 0xFFF) * C_DIM;
        #pragma unroll
        for (int q = 0; q < 4; ++q) {
            ushort8 pv;
            #pragma unroll
            for (int j = 0; j < 8; ++j)
                pv[j] = f2bf(valid ? xrow[c0 + q * 8 + j] : 0.f);
            *(ushort8*)(hfrag + (size_t)((mt * 8 + kt) * 64 + (rr + 16 * q)) * 8) = pv;
        }
    }
    __syncthreads();

    // ---- preload A fragments (x) into registers ----
    bfrag afr[2][8];
    #pragma unroll
    for (int mt = 0; mt < 2; ++mt)
        #pragma unroll
        for (int kt = 0; kt < 8; ++kt)
            afr[mt][kt] = *(const bfrag*)(hfrag + (size_t)((mt * 8 + kt) * 64 + lane) * 8);
    __syncthreads();

    // ---- phase 1: h = gelu(x @ Wfc + bfc); wave w owns frag-cols w*16..w*16+15, depth-2 pipeline ----
    {
        const ushort_t* wb = WfcF + (size_t)e * 512 * 512;
        auto ldB = [&](bfrag* dst, int n1) {
            int nt = w * 16 + n1;
            #pragma unroll
            for (int kt = 0; kt < 8; ++kt)
                dst[kt] = *(const bfrag*)(wb + (size_t)(kt * 64 + nt) * 512 + lane * 8);
        };
        auto wback = [&](const f32x4& a0, const f32x4& a1, int hcol) {
            const int jj = hcol & 7, grp = (hcol & 31) >> 3, kth = hcol >> 5;
            const int rb = (lane >> 4) * 4;
            #pragma unroll
            for (int r = 0; r < 4; ++r) {
                int lp = rb + r + 16 * grp;
                hfrag[(size_t)(kth * 64 + lp) * 8 + jj]        = f2bf(gelu_f(a0[r]));
                hfrag[(size_t)((32 + kth) * 64 + lp) * 8 + jj] = f2bf(gelu_f(a1[r]));
            }
        };
        bfrag bA[8], bB[8];
        ldB(bA, 0);
        ldB(bB, 1);
        #pragma unroll 1
        for (int n1 = 0; n1 < 16; n1 += 2) {
            {
                const int hcol = (w * 16 + n1) * 16 + (lane & 15);
                const float bv = bfc[e * H_DIM + hcol];
                f32x4 a0 = {bv, bv, bv, bv}, a1 = {bv, bv, bv, bv};
                #pragma unroll
                for (int kt = 0; kt < 8; ++kt) {
                    a0 = __builtin_amdgcn_mfma_f32_16x16x32_bf16(afr[0][kt], bA[kt], a0, 0, 0, 0);
                    a1 = __builtin_amdgcn_mfma_f32_16x16x32_bf16(afr[1][kt], bA[kt], a1, 0, 0, 0);
                }
                if (n1 + 2 < 16) ldB(bA, n1 + 2);
                wback(a0, a1, hcol);
            }
            {
                const int hcol = (w * 16 + n1 + 1) * 16 + (lane & 15);
                const float bv = bfc[e * H_DIM + hcol];
                f32x4 a0 = {bv, bv, bv, bv}, a1 = {bv, bv, bv, bv};
                #pragma unroll
                for (int kt = 0; kt < 8; ++kt) {
                    a0 = __builtin_amdgcn_mfma_f32_16x16x32_bf16(afr[0][kt], bB[kt], a0, 0, 0, 0);
                    a1 = __builtin_amdgcn_mfma_f32_16x16x32_bf16(afr[1][kt], bB[kt], a1, 0, 0, 0);
                }
                if (n1 + 3 < 16) ldB(bB, n1 + 3);
                wback(a0, a1, hcol);
            }
        }
    }
    __syncthreads();

    // ---- phase 2: y = h @ Wproj + bproj; wave w owns frag-cols w*4..w*4+3, depth-2 pipeline ----
    f32x4 yac[2][4];
    #pragma unroll
    for (int mt = 0; mt < 2; ++mt)
        #pragma unroll
        for (int q = 0; q < 4; ++q) {
            int ccol = (w * 4 + q) * 16 + (lane & 15);
            float bv = bproj[e * C_DIM + ccol];
            yac[mt][q] = {bv, bv, bv, bv};
        }
    {
        const ushort_t* wb = WprojF + (size_t)e * 512 * 512;
        auto ldBp = [&](bfrag* dst, int kt) {
            #pragma unroll
            for (int q = 0; q < 4; ++q)
                dst[q] = *(const bfrag*)(wb + (size_t)(kt * 16 + w * 4 + q) * 512 + lane * 8);
        };
        auto ldAp = [&](bfrag* dst, int kt) {
            dst[0] = *(const bfrag*)(hfrag + (size_t)(kt * 64 + lane) * 8);
            dst[1] = *(const bfrag*)(hfrag + (size_t)((32 + kt) * 64 + lane) * 8);
        };
        bfrag bA[4], bB[4], aA[2], aB[2];
        ldAp(aA, 0); ldBp(bA, 0);
        ldAp(aB, 1); ldBp(bB, 1);
        #pragma unroll 1
        for (int kt = 0; kt < 32; kt += 2) {
            #pragma unroll
            for (int q = 0; q < 4; ++q) {
                yac[0][q] = __builtin_amdgcn_mfma_f32_16x16x32_bf16(aA[0], bA[q], yac[0][q], 0, 0, 0);
                yac[1][q] = __builtin_amdgcn_mfma_f32_16x16x32_bf16(aA[1], bA[q], yac[1][q], 0, 0, 0);
            }
            if (kt + 2 < 32) { ldBp(bA, kt + 2); ldAp(aA, kt + 2); }
            #pragma unroll
            for (int q = 0; q < 4; ++q) {
                yac[0][q] = __builtin_amdgcn_mfma_f32_16x16x32_bf16(aB[0], bB[q], yac[0][q], 0, 0, 0);
                yac[1][q] = __builtin_amdgcn_mfma_f32_16x16x32_bf16(aB[1], bB[q], yac[1][q], 0, 0, 0);
            }
            if (kt + 3 < 32) { ldBp(bB, kt + 3); ldAp(aB, kt + 3); }
        }
    }
    __syncthreads();

    // ---- y (f32) to LDS natural layout [32][260] (reuses hfrag) ----
    float* ynat = (float*)hfrag;   // 32*260*4 = 33280 B
    #pragma unroll
    for (int mt = 0; mt < 2; ++mt)
        #pragma unroll
        for (int q = 0; q < 4; ++q) {
            int ccol = (w * 4 + q) * 16 + (lane & 15);
            #pragma unroll
            for (int r = 0; r < 4; ++r) {
                int tt = mt * 16 + (lane >> 4) * 4 + r;
                ynat[tt * 260 + ccol] = yac[mt][q][r];
            }
        }
    __syncthreads();

    // ---- epilogue: wave w handles tokens [w*8, w*8+8); butterfly reduce, float4 store ----
    {
        const float cc0 = cptr[0];
        const float rsqc = sqrtf(cc0);
        #pragma unroll 1
        for (int i = 0; i < 8; ++i) {
            int tt = w * 8 + i;
            if (tt >= ntk) break;
            int pk = spk[tt];
            int tok = pk & 0xFFF, slot = pk >> 12;
            float4 yv = *(const float4*)(ynat + tt * 260 + lane * 4);
            float4 rv = *(const float4*)(rfp + (size_t)tok * C_DIM + lane * 4);
            float s2  = yv.x * yv.x + yv.y * yv.y + yv.z * yv.z + yv.w * yv.w;
            float sxy = rv.x * yv.x + rv.y * yv.y + rv.z * yv.z + rv.w * yv.w;
            #pragma unroll
            for (int off = 32; off; off >>= 1) {
                s2  += __shfl_xor(s2, off);
                sxy += __shfl_xor(sxy, off);
            }
            float ref2 = ref2p[tok];
            float sf = 2.f / (1.f + cc0 * ref2);
            float vn = sqrtf(s2);
            float aa = sqrtf(cc0 * sf * 0.5f);
            float alpha = (vn > 1e-20f) ? (tanhf(aa * vn) / (vn * rsqc)) : (aa / rsqc);
            float axy = alpha * sxy;
            float ay2 = alpha * alpha * s2;
            float A   = 1.f + 2.f * cc0 * axy + cc0 * ay2;
            float Bc  = (1.f - cc0 * ref2) * alpha;
            float den = 1.f + 2.f * cc0 * axy + cc0 * cc0 * ref2 * ay2;
            float wi  = swgt[tt] / den;
            float aco = A * wi, bco = Bc * wi;
            float4 o;
            o.x = fmaf(aco, rv.x, bco * yv.x);
            o.y = fmaf(aco, rv.y, bco * yv.y);
            o.z = fmaf(aco, rv.z, bco * yv.z);
            o.w = fmaf(aco, rv.w, bco * yv.w);
            *(float4*)(part + ((size_t)slot * N_TOK + tok) * C_DIM + lane * 4) = o;
        }
    }
}

// ---------------- combine: out = sum of 4 part slots (float4) ----------------
__global__ __launch_bounds__(256) void combine_kernel(
    const float* __restrict__ part, float* __restrict__ out)
{
    const size_t NC = (size_t)N_TOK * C_DIM;
    size_t i = ((size_t)blockIdx.x * 256 + threadIdx.x) * 4;
    float4 a = *(const float4*)(part + i);
    float4 b = *(const float4*)(part + i + NC);
    float4 c = *(const float4*)(part + i + 2 * NC);
    float4 d = *(const float4*)(part + i + 3 * NC);
    float4 o;
    o.x = (a.x + b.x) + (c.x + d.x);
    o.y = (a.y + b.y) + (c.y + d.y);
    o.z = (a.z + b.z) + (c.z + d.z);
    o.w = (a.w + b.w) + (c.w + d.w);
    *(float4*)(out + i) = o;
}

// ---------------- fallback fp32 expert kernel (round-1, proven) ----------------
__global__ __launch_bounds__(256) void expert_kernel(
    const float* __restrict__ xf, const float* __restrict__ rfp,
    const float* __restrict__ Wfc, const float* __restrict__ bfc,
    const float* __restrict__ Wproj, const float* __restrict__ bproj,
    const float* __restrict__ cptr, const float* __restrict__ ref2p,
    const int* __restrict__ counts, const int* __restrict__ btok,
    const float* __restrict__ bwgt, float* __restrict__ out)
{
    const int e = blockIdx.x;
    const int cnt = counts[e];
    const int base = blockIdx.y * TT;
    if (base >= cnt) return;
    const int nt = min(TT, cnt - base);
    const int j = threadIdx.x;

    __shared__ __align__(16) float xs[TT * C_DIM];
    __shared__ __align__(16) float hs[TT * C_DIM];
    __shared__ int   stok[TT];
    __shared__ float swgt[TT];
    __shared__ float scA[TT], scB[TT];

    if (j < nt) {
        stok[j] = btok[(size_t)e * N_TOK + base + j] & 0xFFF;
        swgt[j] = bwgt[(size_t)e * N_TOK + base + j];
    }
    __syncthreads();
    for (int t = 0; t < nt; ++t) xs[t * C_DIM + j] = xf[(size_t)stok[t] * C_DIM + j];
    for (int t = nt; t < TT; ++t) xs[t * C_DIM + j] = 0.f;
    __syncthreads();

    const float* Wfc_e = Wfc + (size_t)e * C_DIM * H_DIM;
    float h[4][TT];
    {
        float bk[4];
        #pragma unroll
        for (int k = 0; k < 4; ++k) bk[k] = bfc[(size_t)e * H_DIM + j + k * 256];
        #pragma unroll
        for (int k = 0; k < 4; ++k)
            #pragma unroll
            for (int tt = 0; tt < TT; ++tt) h[k][tt] = bk[k];
    }
    for (int c0 = 0; c0 < C_DIM; c0 += 4) {
        float wv[4][4];
        #pragma unroll
        for (int ci = 0; ci < 4; ++ci) {
            const float* wp = Wfc_e + (size_t)(c0 + ci) * H_DIM + j;
            wv[ci][0] = wp[0]; wv[ci][1] = wp[256]; wv[ci][2] = wp[512]; wv[ci][3] = wp[768];
        }
        #pragma unroll
        for (int tt = 0; tt < TT; ++tt) {
            float4 xv = *(const float4*)(xs + tt * C_DIM + c0);
            #pragma unroll
            for (int k = 0; k < 4; ++k)
                h[k][tt] += xv.x * wv[0][k] + xv.y * wv[1][k] + xv.z * wv[2][k] + xv.w * wv[3][k];
        }
    }
    #pragma unroll
    for (int k = 0; k < 4; ++k)
        #pragma unroll
        for (int tt = 0; tt < TT; ++tt) {
            float v = h[k][tt];
            h[k][tt] = 0.5f * v * (1.f + erff(v * 0.70710678118f));
        }

    const float* Wp_e = Wproj + (size_t)e * H_DIM * C_DIM;
    float yacc[TT];
    {
        float bp = bproj[(size_t)e * C_DIM + j];
        #pragma unroll
        for (int tt = 0; tt < TT; ++tt) yacc[tt] = bp;
    }
    #pragma unroll
    for (int k = 0; k < 4; ++k) {
        __syncthreads();
        #pragma unroll
        for (int tt = 0; tt < TT; ++tt) hs[tt * C_DIM + j] = h[k][tt];
        __syncthreads();
        for (int h0 = 0; h0 < 256; h0 += 4) {
            float wv[4];
            #pragma unroll
            for (int hi = 0; hi < 4; ++hi)
                wv[hi] = Wp_e[(size_t)(k * 256 + h0 + hi) * C_DIM + j];
            #pragma unroll
            for (int tt = 0; tt < TT; ++tt) {
                float4 hv = *(const float4*)(hs + tt * C_DIM + h0);
                yacc[tt] += hv.x * wv[0] + hv.y * wv[1] + hv.z * wv[2] + hv.w * wv[3];
            }
        }
    }

    __syncthreads();
    #pragma unroll
    for (int tt = 0; tt < TT; ++tt) hs[tt * C_DIM + j] = yacc[tt];
    __syncthreads();

    const float cc0 = cptr[0];
    const int wave = j >> 6, lane = j & 63;
    for (int q = 0; q < 4; ++q) {
        int tt = wave * 4 + q;
        if (tt >= nt) break;
        int tok = stok[tt];
        float s2 = 0.f, sxy = 0.f;
        #pragma unroll
        for (int m = 0; m < 4; ++m) {
            int ccol = lane + 64 * m;
            float yv = hs[tt * C_DIM + ccol];
            float rv = rfp[(size_t)tok * C_DIM + ccol];
            s2 += yv * yv; sxy += rv * yv;
        }
        #pragma unroll
        for (int off = 32; off; off >>= 1) {
            s2  += __shfl_down(s2, off);
            sxy += __shfl_down(sxy, off);
        }
        if (lane == 0) {
            float ref2 = ref2p[tok];
            float sf = 2.f / (1.f + cc0 * ref2);
            float vn = sqrtf(s2);
            float a = sqrtf(cc0 * sf * 0.5f);
            float alpha = (vn > 1e-20f)
                        ? (tanhf(a * vn) / (vn * sqrtf(cc0)))
                        : (a / sqrtf(cc0));
            float axy = alpha * sxy;
            float ay2 = alpha * alpha * s2;
            float A   = 1.f + 2.f * cc0 * axy + cc0 * ay2;
            float Bc  = (1.f - cc0 * ref2) * alpha;
            float den = 1.f + 2.f * cc0 * axy + cc0 * cc0 * ref2 * ay2;
            float wi  = swgt[tt] / den;
            scA[tt] = A * wi;
            scB[tt] = Bc * wi;
        }
    }
    __syncthreads();

    for (int tt = 0; tt < nt; ++tt) {
        int tok = stok[tt];
        float rv = rfp[(size_t)tok * C_DIM + j];
        float yv = hs[tt * C_DIM + j];
        atomicAdd(&out[(size_t)tok * C_DIM + j], scA[tt] * rv + scB[tt] * yv);
    }
}

extern "C" void kernel_launch(void* const* d_in, const int* in_sizes, int n_in,
                              void* d_out, int out_size, void* d_ws, size_t ws_size,
                              hipStream_t stream) {
    (void)in_sizes; (void)n_in; (void)out_size;
    const float* x     = (const float*)d_in[0];
    const float* rfp   = (const float*)d_in[1];
    const float* Wg    = (const float*)d_in[2];
    const float* bg    = (const float*)d_in[3];
    const float* ebias = (const float*)d_in[4];
    const float* Wfc   = (const float*)d_in[5];
    const float* bfc   = (const float*)d_in[6];
    const float* Wproj = (const float*)d_in[7];
    const float* bproj = (const float*)d_in[8];
    const float* cptr  = (const float*)d_in[9];

    float* out = (float*)d_out;                       // [n, C]
    float* rw  = out + (size_t)N_TOK * C_DIM;         // [n, E]

    constexpr size_t OFF_BTOK  = 128;
    constexpr size_t OFF_BWGT  = OFF_BTOK + (size_t)E_DIM * N_TOK * 4;
    constexpr size_t OFF_REF2  = OFF_BWGT + (size_t)E_DIM * N_TOK * 4;
    constexpr size_t OFF_TBL   = ((OFF_REF2 + (size_t)N_TOK * 4 + 255) / 256) * 256;
    constexpr size_t OFF_WFC   = OFF_TBL + 4096;
    constexpr size_t SZ_W      = (size_t)E_DIM * C_DIM * H_DIM * 2;  // 16 MB bf16 each
    constexpr size_t OFF_WPROJ = OFF_WFC + SZ_W;
    constexpr size_t OFF_PART  = OFF_WPROJ + SZ_W;
    constexpr size_t SZ_PART   = (size_t)4 * N_TOK * C_DIM * 4;      // 16 MB
    constexpr size_t WS_FULL   = OFF_PART + SZ_PART;

    char* ws = (char*)d_ws;
    int*   counts = (int*)ws;
    int*   btok   = (int*)(ws + OFF_BTOK);
    float* bwgt   = (float*)(ws + OFF_BWGT);
    float* ref2   = (float*)(ws + OFF_REF2);
    int*   tbl    = (int*)(ws + OFF_TBL);

    hipMemsetAsync(counts, 0, E_DIM * sizeof(int), stream);

    if (ws_size >= WS_FULL) {
        ushort_t* WfcF   = (ushort_t*)(ws + OFF_WFC);
        ushort_t* WprojF = (ushort_t*)(ws + OFF_WPROJ);
        float*    part   = (float*)(ws + OFF_PART);
        // fused: 512 Wfc-transpose + 1024 Wproj-transpose + 1024 gate blocks
        const int NFC = E_DIM * 8 * 2;          // 512
        const int NWT = NFC + E_DIM * 32;       // 1536
        prep_kernel<<<NWT + 1024, 256, 0, stream>>>(
            Wfc, Wproj, WfcF, WprojF, x, rfp, Wg, bg, ebias,
            rw, counts, btok, bwgt, ref2, NFC, NWT);
        finalize_kernel<<<1, 64, 0, stream>>>(counts, tbl);
        expert_mfma32p<<<TBL_MAX, 256, 0, stream>>>(x, rfp, WfcF, WprojF, bfc, bproj,
                                                    cptr, ref2, counts, btok, bwgt, tbl, part);
        combine_kernel<<<(N_TOK * C_DIM) / 1024, 256, 0, stream>>>(part, out);
    } else {
        hipMemsetAsync(out, 0, (size_t)N_TOK * C_DIM * sizeof(float), stream);
        prep_kernel<<<1024, 256, 0, stream>>>(
            Wfc, Wproj, nullptr, nullptr, x, rfp, Wg, bg, ebias,
            rw, counts, btok, bwgt, ref2, 0, 0);
        dim3 grid(E_DIM, N_TOK / TT);
        expert_kernel<<<grid, 256, 0, stream>>>(x, rfp, Wfc, bfc, Wproj, bproj,
                                                cptr, ref2, counts, btok, bwgt, out);
    }
}

// Round 7
// 125.704 us; speedup vs baseline: 1.5169x; 1.5169x over previous
//
#include <hip/hip_runtime.h>
#include <math.h>

#define N_TOK 4096
#define C_DIM 256
#define G_DIM 31
#define E_DIM 32
#define H_DIM 1024
#define TT    16   // fp32 fallback tile
#define MT    32   // mfma tile tokens
#define TBL_MAX 576

typedef unsigned short ushort_t;
typedef unsigned int uint_t;
typedef __attribute__((ext_vector_type(8))) short bfrag;
typedef __attribute__((ext_vector_type(4))) float f32x4;
typedef __attribute__((ext_vector_type(8))) unsigned short ushort8;

__device__ __forceinline__ ushort_t f2bf(float f) {
    uint_t u = __float_as_uint(f);
    uint_t r = (u + 0x7fffu + ((u >> 16) & 1u)) >> 16;
    return (ushort_t)r;
}

__device__ __forceinline__ float gelu_f(float v) {
    float u = 0.7978845608f * fmaf(0.044715f * v * v, v, v);
    float t = __expf(-2.f * u);
    return 0.5f * v * (1.f + (1.f - t) / (1.f + t));
}

// ---------------- weight transform: unified 32x256 tiles, register-staged loads ----------------
// grid = E_DIM * 64 blocks; sub<32 -> Wfc (kt=sub>>2, quarter=sub&3), sub>=32 -> Wproj (kt=sub-32)
// WfcF  frag block id = e*512 + kt*64 + nt_global (nt_global = h/16)
// WprojF frag block id = e*512 + kt*16 + nt       (nt = c/16)
// Within frag block: lane's 8 bf16 = B[k0+(lane>>4)*8+j][n0+(lane&15)]
__global__ __launch_bounds__(256) void wtrans_kernel(
    const float* __restrict__ Wfc, const float* __restrict__ Wproj,
    ushort_t* __restrict__ WfcF, ushort_t* __restrict__ WprojF)
{
    __shared__ __align__(16) ushort_t s[32][260];   // 16640 B -> 8 blocks/CU
    const int tid = threadIdx.x;
    const int b = blockIdx.x;
    const int e = b >> 6, sub = b & 63;
    const bool isfc = sub < 32;
    const float* src;
    int stride, fbbase;
    if (isfc) {
        int kt = sub >> 2, q = sub & 3;
        src = Wfc + ((size_t)e << 18) + (size_t)(kt * 32) * H_DIM + q * 256;
        stride = H_DIM;
        fbbase = e * 512 + kt * 64 + q * 16;
    } else {
        int kt = sub - 32;
        src = Wproj + ((size_t)e << 18) + (size_t)(kt * 32) * C_DIM;
        stride = C_DIM;
        fbbase = e * 512 + kt * 16;
    }
    ushort_t* dst = isfc ? WfcF : WprojF;

    // stage all 8 float4 loads in registers first (keeps 8 loads in flight)
    float4 v[8];
    #pragma unroll
    for (int i = 0; i < 8; ++i) {
        int flat = i * 256 + tid;          // 0..2047 float4 slots
        int r = flat >> 6, q4 = flat & 63; // 64 float4 per 256-col row
        v[i] = *(const float4*)(src + (size_t)r * stride + q4 * 4);
    }
    #pragma unroll
    for (int i = 0; i < 8; ++i) {
        int flat = i * 256 + tid;
        int r = flat >> 6, q4 = flat & 63;
        s[r][q4 * 4 + 0] = f2bf(v[i].x);
        s[r][q4 * 4 + 1] = f2bf(v[i].y);
        s[r][q4 * 4 + 2] = f2bf(v[i].z);
        s[r][q4 * 4 + 3] = f2bf(v[i].w);
    }
    __syncthreads();

    const int l = tid & 63, w = tid >> 6;
    #pragma unroll
    for (int t = 0; t < 4; ++t) {
        int nt = w + t * 4;                // 0..15
        ushort8 pv;
        #pragma unroll
        for (int j = 0; j < 8; ++j)
            pv[j] = s[(l >> 4) * 8 + j][nt * 16 + (l & 15)];
        *(ushort8*)(dst + ((size_t)(fbbase + nt) * 64 + l) * 8) = pv;
    }
}

// ---------------- gate: wave per token, atomic-free ----------------
// writes: rw row, ref2, expert-0 bucket entry, choice[tok] = {w1,w2,w3, pack(e1,e2,e3)}
__global__ __launch_bounds__(256) void gate_kernel(
    const float* __restrict__ xf, const float* __restrict__ rfp,
    const float* __restrict__ Wg, const float* __restrict__ bg,
    const float* __restrict__ ebias,
    float* __restrict__ rw_out, int* __restrict__ btok,
    float* __restrict__ bwgt, float* __restrict__ ref2_out,
    float4* __restrict__ choice)
{
    __shared__ float wgS[C_DIM * G_DIM];   // 31744 B
    __shared__ __align__(16) float xs[4][C_DIM];
    const int tid = threadIdx.x;
    const int w = tid >> 6, l = tid & 63;
    const int tok = blockIdx.x * 4 + w;

    for (int i = tid; i < C_DIM * G_DIM; i += 256) wgS[i] = Wg[i];

    float4 xv = *(const float4*)(xf + (size_t)tok * C_DIM + l * 4);
    float4 rv = *(const float4*)(rfp + (size_t)tok * C_DIM + l * 4);
    *(float4*)(&xs[w][l * 4]) = xv;
    float r2 = rv.x * rv.x + rv.y * rv.y + rv.z * rv.z + rv.w * rv.w;
    #pragma unroll
    for (int off = 32; off; off >>= 1) r2 += __shfl_xor(r2, off);
    if (l == 0) ref2_out[tok] = r2;
    __syncthreads();

    const int g = l & 31, half = l >> 5;
    float acc = 0.f;
    if (g < G_DIM) {
        const float* xr = xs[w] + half * 128;
        const float* wg = wgS + (size_t)(half * 128) * G_DIM + g;
        #pragma unroll 8
        for (int c = 0; c < 128; ++c)
            acc = fmaf(xr[c], wg[(size_t)c * G_DIM], acc);
    }
    acc += __shfl_xor(acc, 32);
    float lg = acc + ((g < G_DIM) ? bg[g] : 0.f);

    float v = (l < G_DIM) ? lg : -1e30f;
    float m = v;
    #pragma unroll
    for (int off = 32; off; off >>= 1) m = fmaxf(m, __shfl_xor(m, off));
    float pex = (l < G_DIM) ? __expf(v - m) : 0.f;
    float s = pex;
    #pragma unroll
    for (int off = 32; off; off >>= 1) s += __shfl_xor(s, off);
    float p = (l < G_DIM) ? (pex / s + ebias[l]) : -1e30f;

    float w3[3]; int id3[3];
    float vv = p;
    #pragma unroll
    for (int t = 0; t < 3; ++t) {
        float bv = vv; int bi = l;
        #pragma unroll
        for (int off = 32; off; off >>= 1) {
            float ov = __shfl_xor(bv, off); int oi = __shfl_xor(bi, off);
            if (ov > bv || (ov == bv && oi < bi)) { bv = ov; bi = oi; }
        }
        w3[t] = bv; id3[t] = bi;
        if (l == bi) vv = -1e30f;
    }
    float vs = w3[0] + w3[1] + w3[2];
    #pragma unroll
    for (int t = 0; t < 3; ++t) w3[t] = (w3[t] / vs) * 0.75f;

    if (l < 32) {
        float r = (l == 0) ? 0.25f : 0.f;
        #pragma unroll
        for (int t = 0; t < 3; ++t) if (l == id3[t] + 1) r = w3[t];
        rw_out[(size_t)tok * E_DIM + l] = r;
    }

    if (l == 0) {
        btok[tok] = tok;          // expert 0, slot 0
        bwgt[tok] = 0.25f;
        int packed = (id3[0] + 1) | ((id3[1] + 1) << 8) | ((id3[2] + 1) << 16);
        float4 ch;
        ch.x = w3[0]; ch.y = w3[1]; ch.z = w3[2]; ch.w = __int_as_float(packed);
        choice[tok] = ch;
    }
}

// ---------------- bucketize: block e+1 compacts its token list (no atomics, deterministic) ----------------
__global__ __launch_bounds__(256) void bucketize_kernel(
    const float4* __restrict__ choice, int* __restrict__ btok,
    float* __restrict__ bwgt, int* __restrict__ counts)
{
    const int e = blockIdx.x + 1;          // experts 1..31
    const int tid = threadIdx.x;
    const int l = tid & 63, w = tid >> 6;
    __shared__ int wsum[4];

    int base = 0;
    for (int chunk = 0; chunk < N_TOK; chunk += 256) {
        int tok = chunk + tid;
        float4 ch = choice[tok];
        int eids = __float_as_int(ch.w);
        int m = 0; float wv = 0.f;
        if ((eids & 255) == e)              { m = 1; wv = ch.x; }
        else if (((eids >> 8) & 255) == e)  { m = 2; wv = ch.y; }
        else if (((eids >> 16) & 255) == e) { m = 3; wv = ch.z; }
        int x = m ? 1 : 0;
        #pragma unroll
        for (int off = 1; off < 64; off <<= 1) {
            int y = __shfl_up(x, off);
            if (l >= off) x += y;
        }
        if (l == 63) wsum[w] = x;
        __syncthreads();
        int waveoff = 0;
        #pragma unroll
        for (int i = 0; i < 4; ++i) if (i < w) waveoff += wsum[i];
        int total = wsum[0] + wsum[1] + wsum[2] + wsum[3];
        if (m) {
            int pos = base + waveoff + x - 1;
            btok[(size_t)e * N_TOK + pos] = tok | (m << 12);
            bwgt[(size_t)e * N_TOK + pos] = wv;
        }
        base += total;
        __syncthreads();   // protect wsum reuse next chunk
    }
    if (tid == 0) {
        counts[e] = base;
        if (e == 1) counts[0] = N_TOK;
    }
}

// ---------------- finalize: compact (expert,tile) table + total ----------------
__global__ __launch_bounds__(64) void finalize_kernel(
    const int* __restrict__ counts, int* __restrict__ tbl)
{
    const int l = threadIdx.x;
    int cnt = (l < E_DIM) ? counts[l] : 0;
    int tiles = (cnt + MT - 1) / MT;
    int x = tiles;
    #pragma unroll
    for (int off = 1; off < 64; off <<= 1) {
        int y = __shfl_up(x, off);
        if (l >= off) x += y;
    }
    int base = x - tiles;
    if (l == 63) tbl[0] = x;
    if (l < E_DIM)
        for (int t = 0; t < tiles; ++t)
            tbl[1 + base + t] = l | (t << 8);
}

// ---------------- MFMA expert kernel: 32 tokens, depth-2 pipelined, compacted grid ----------------
__global__ __launch_bounds__(256, 2) void expert_mfma32p(
    const float* __restrict__ xf, const float* __restrict__ rfp,
    const ushort_t* __restrict__ WfcF, const ushort_t* __restrict__ WprojF,
    const float* __restrict__ bfc, const float* __restrict__ bproj,
    const float* __restrict__ cptr, const float* __restrict__ ref2p,
    const int* __restrict__ counts, const int* __restrict__ btok,
    const float* __restrict__ bwgt, const int* __restrict__ tbl,
    float* __restrict__ part)
{
    const int T = (blockIdx.x & 7) * (TBL_MAX / 8) + (blockIdx.x >> 3);
    const int tot = tbl[0];
    if (T >= tot) return;
    const int ent = tbl[1 + T];
    const int e = ent & 0xFF;
    const int base = (ent >> 8) * MT;
    const int cnt = counts[e];
    const int ntk = min(MT, cnt - base);
    const int tid = threadIdx.x;
    const int lane = tid & 63;
    const int w = tid >> 6;

    __shared__ __align__(16) ushort_t hfrag[MT * H_DIM];  // 64 KB
    __shared__ int   spk[MT];
    __shared__ float swgt[MT];

    if (tid < MT) {
        bool vld = (base + tid) < cnt;
        spk[tid]  = btok[(size_t)e * N_TOK + (vld ? base + tid : base)];
        swgt[tid] = vld ? bwgt[(size_t)e * N_TOK + base + tid] : 0.f;
    }
    __syncthreads();

    {
        const int r  = tid >> 3;
        const int c0 = (tid & 7) * 32;
        const int mt = r >> 4, rr = r & 15;
        const int kt = c0 >> 5;
        const bool valid = (r < ntk);
        const float* xrow = xf + (size_t)(spk[r] & 0xFFF) * C_DIM;
        #pragma unroll
        for (int q = 0; q < 4; ++q) {
            ushort8 pv;
            #pragma unroll
            for (int j = 0; j < 8; ++j)
                pv[j] = f2bf(valid ? xrow[c0 + q * 8 + j] : 0.f);
            *(ushort8*)(hfrag + (size_t)((mt * 8 + kt) * 64 + (rr + 16 * q)) * 8) = pv;
        }
    }
    __syncthreads();

    bfrag afr[2][8];
    #pragma unroll
    for (int mt = 0; mt < 2; ++mt)
        #pragma unroll
        for (int kt = 0; kt < 8; ++kt)
            afr[mt][kt] = *(const bfrag*)(hfrag + (size_t)((mt * 8 + kt) * 64 + lane) * 8);
    __syncthreads();

    {
        const ushort_t* wb = WfcF + (size_t)e * 512 * 512;
        auto ldB = [&](bfrag* dst, int n1) {
            int nt = w * 16 + n1;
            #pragma unroll
            for (int kt = 0; kt < 8; ++kt)
                dst[kt] = *(const bfrag*)(wb + (size_t)(kt * 64 + nt) * 512 + lane * 8);
        };
        auto wback = [&](const f32x4& a0, const f32x4& a1, int hcol) {
            const int jj = hcol & 7, grp = (hcol & 31) >> 3, kth = hcol >> 5;
            const int rb = (lane >> 4) * 4;
            #pragma unroll
            for (int r = 0; r < 4; ++r) {
                int lp = rb + r + 16 * grp;
                hfrag[(size_t)(kth * 64 + lp) * 8 + jj]        = f2bf(gelu_f(a0[r]));
                hfrag[(size_t)((32 + kth) * 64 + lp) * 8 + jj] = f2bf(gelu_f(a1[r]));
            }
        };
        bfrag bA[8], bB[8];
        ldB(bA, 0);
        ldB(bB, 1);
        #pragma unroll 1
        for (int n1 = 0; n1 < 16; n1 += 2) {
            {
                const int hcol = (w * 16 + n1) * 16 + (lane & 15);
                const float bv = bfc[e * H_DIM + hcol];
                f32x4 a0 = {bv, bv, bv, bv}, a1 = {bv, bv, bv, bv};
                #pragma unroll
                for (int kt = 0; kt < 8; ++kt) {
                    a0 = __builtin_amdgcn_mfma_f32_16x16x32_bf16(afr[0][kt], bA[kt], a0, 0, 0, 0);
                    a1 = __builtin_amdgcn_mfma_f32_16x16x32_bf16(afr[1][kt], bA[kt], a1, 0, 0, 0);
                }
                if (n1 + 2 < 16) ldB(bA, n1 + 2);
                wback(a0, a1, hcol);
            }
            {
                const int hcol = (w * 16 + n1 + 1) * 16 + (lane & 15);
                const float bv = bfc[e * H_DIM + hcol];
                f32x4 a0 = {bv, bv, bv, bv}, a1 = {bv, bv, bv, bv};
                #pragma unroll
                for (int kt = 0; kt < 8; ++kt) {
                    a0 = __builtin_amdgcn_mfma_f32_16x16x32_bf16(afr[0][kt], bB[kt], a0, 0, 0, 0);
                    a1 = __builtin_amdgcn_mfma_f32_16x16x32_bf16(afr[1][kt], bB[kt], a1, 0, 0, 0);
                }
                if (n1 + 3 < 16) ldB(bB, n1 + 3);
                wback(a0, a1, hcol);
            }
        }
    }
    __syncthreads();

    f32x4 yac[2][4];
    #pragma unroll
    for (int mt = 0; mt < 2; ++mt)
        #pragma unroll
        for (int q = 0; q < 4; ++q) {
            int ccol = (w * 4 + q) * 16 + (lane & 15);
            float bv = bproj[e * C_DIM + ccol];
            yac[mt][q] = {bv, bv, bv, bv};
        }
    {
        const ushort_t* wb = WprojF + (size_t)e * 512 * 512;
        auto ldBp = [&](bfrag* dst, int kt) {
            #pragma unroll
            for (int q = 0; q < 4; ++q)
                dst[q] = *(const bfrag*)(wb + (size_t)(kt * 16 + w * 4 + q) * 512 + lane * 8);
        };
        auto ldAp = [&](bfrag* dst, int kt) {
            dst[0] = *(const bfrag*)(hfrag + (size_t)(kt * 64 + lane) * 8);
            dst[1] = *(const bfrag*)(hfrag + (size_t)((32 + kt) * 64 + lane) * 8);
        };
        bfrag bA[4], bB[4], aA[2], aB[2];
        ldAp(aA, 0); ldBp(bA, 0);
        ldAp(aB, 1); ldBp(bB, 1);
        #pragma unroll 1
        for (int kt = 0; kt < 32; kt += 2) {
            #pragma unroll
            for (int q = 0; q < 4; ++q) {
                yac[0][q] = __builtin_amdgcn_mfma_f32_16x16x32_bf16(aA[0], bA[q], yac[0][q], 0, 0, 0);
                yac[1][q] = __builtin_amdgcn_mfma_f32_16x16x32_bf16(aA[1], bA[q], yac[1][q], 0, 0, 0);
            }
            if (kt + 2 < 32) { ldBp(bA, kt + 2); ldAp(aA, kt + 2); }
            #pragma unroll
            for (int q = 0; q < 4; ++q) {
                yac[0][q] = __builtin_amdgcn_mfma_f32_16x16x32_bf16(aB[0], bB[q], yac[0][q], 0, 0, 0);
                yac[1][q] = __builtin_amdgcn_mfma_f32_16x16x32_bf16(aB[1], bB[q], yac[1][q], 0, 0, 0);
            }
            if (kt + 3 < 32) { ldBp(bB, kt + 3); ldAp(aB, kt + 3); }
        }
    }
    __syncthreads();

    float* ynat = (float*)hfrag;   // 32*260*4 = 33280 B
    #pragma unroll
    for (int mt = 0; mt < 2; ++mt)
        #pragma unroll
        for (int q = 0; q < 4; ++q) {
            int ccol = (w * 4 + q) * 16 + (lane & 15);
            #pragma unroll
            for (int r = 0; r < 4; ++r) {
                int tt = mt * 16 + (lane >> 4) * 4 + r;
                ynat[tt * 260 + ccol] = yac[mt][q][r];
            }
        }
    __syncthreads();

    {
        const float cc0 = cptr[0];
        const float rsqc = sqrtf(cc0);
        #pragma unroll 1
        for (int i = 0; i < 8; ++i) {
            int tt = w * 8 + i;
            if (tt >= ntk) break;
            int pk = spk[tt];
            int tok = pk & 0xFFF, slot = pk >> 12;
            float4 yv = *(const float4*)(ynat + tt * 260 + lane * 4);
            float4 rv = *(const float4*)(rfp + (size_t)tok * C_DIM + lane * 4);
            float s2  = yv.x * yv.x + yv.y * yv.y + yv.z * yv.z + yv.w * yv.w;
            float sxy = rv.x * yv.x + rv.y * yv.y + rv.z * yv.z + rv.w * yv.w;
            #pragma unroll
            for (int off = 32; off; off >>= 1) {
                s2  += __shfl_xor(s2, off);
                sxy += __shfl_xor(sxy, off);
            }
            float ref2 = ref2p[tok];
            float sf = 2.f / (1.f + cc0 * ref2);
            float vn = sqrtf(s2);
            float aa = sqrtf(cc0 * sf * 0.5f);
            float alpha = (vn > 1e-20f) ? (tanhf(aa * vn) / (vn * rsqc)) : (aa / rsqc);
            float axy = alpha * sxy;
            float ay2 = alpha * alpha * s2;
            float A   = 1.f + 2.f * cc0 * axy + cc0 * ay2;
            float Bc  = (1.f - cc0 * ref2) * alpha;
            float den = 1.f + 2.f * cc0 * axy + cc0 * cc0 * ref2 * ay2;
            float wi  = swgt[tt] / den;
            float aco = A * wi, bco = Bc * wi;
            float4 o;
            o.x = fmaf(aco, rv.x, bco * yv.x);
            o.y = fmaf(aco, rv.y, bco * yv.y);
            o.z = fmaf(aco, rv.z, bco * yv.z);
            o.w = fmaf(aco, rv.w, bco * yv.w);
            *(float4*)(part + ((size_t)slot * N_TOK + tok) * C_DIM + lane * 4) = o;
        }
    }
}

// ---------------- combine: out = sum of 4 part slots (float4) ----------------
__global__ __launch_bounds__(256) void combine_kernel(
    const float* __restrict__ part, float* __restrict__ out)
{
    const size_t NC = (size_t)N_TOK * C_DIM;
    size_t i = ((size_t)blockIdx.x * 256 + threadIdx.x) * 4;
    float4 a = *(const float4*)(part + i);
    float4 b = *(const float4*)(part + i + NC);
    float4 c = *(const float4*)(part + i + 2 * NC);
    float4 d = *(const float4*)(part + i + 3 * NC);
    float4 o;
    o.x = (a.x + b.x) + (c.x + d.x);
    o.y = (a.y + b.y) + (c.y + d.y);
    o.z = (a.z + b.z) + (c.z + d.z);
    o.w = (a.w + b.w) + (c.w + d.w);
    *(float4*)(out + i) = o;
}

// ---------------- fallback fp32 expert kernel ----------------
__global__ __launch_bounds__(256) void expert_kernel(
    const float* __restrict__ xf, const float* __restrict__ rfp,
    const float* __restrict__ Wfc, const float* __restrict__ bfc,
    const float* __restrict__ Wproj, const float* __restrict__ bproj,
    const float* __restrict__ cptr, const float* __restrict__ ref2p,
    const int* __restrict__ counts, const int* __restrict__ btok,
    const float* __restrict__ bwgt, float* __restrict__ out)
{
    const int e = blockIdx.x;
    const int cnt = counts[e];
    const int base = blockIdx.y * TT;
    if (base >= cnt) return;
    const int nt = min(TT, cnt - base);
    const int j = threadIdx.x;

    __shared__ __align__(16) float xs[TT * C_DIM];
    __shared__ __align__(16) float hs[TT * C_DIM];
    __shared__ int   stok[TT];
    __shared__ float swgt[TT];
    __shared__ float scA[TT], scB[TT];

    if (j < nt) {
        stok[j] = btok[(size_t)e * N_TOK + base + j] & 0xFFF;
        swgt[j] = bwgt[(size_t)e * N_TOK + base + j];
    }
    __syncthreads();
    for (int t = 0; t < nt; ++t) xs[t * C_DIM + j] = xf[(size_t)stok[t] * C_DIM + j];
    for (int t = nt; t < TT; ++t) xs[t * C_DIM + j] = 0.f;
    __syncthreads();

    const float* Wfc_e = Wfc + (size_t)e * C_DIM * H_DIM;
    float h[4][TT];
    {
        float bk[4];
        #pragma unroll
        for (int k = 0; k < 4; ++k) bk[k] = bfc[(size_t)e * H_DIM + j + k * 256];
        #pragma unroll
        for (int k = 0; k < 4; ++k)
            #pragma unroll
            for (int tt = 0; tt < TT; ++tt) h[k][tt] = bk[k];
    }
    for (int c0 = 0; c0 < C_DIM; c0 += 4) {
        float wv[4][4];
        #pragma unroll
        for (int ci = 0; ci < 4; ++ci) {
            const float* wp = Wfc_e + (size_t)(c0 + ci) * H_DIM + j;
            wv[ci][0] = wp[0]; wv[ci][1] = wp[256]; wv[ci][2] = wp[512]; wv[ci][3] = wp[768];
        }
        #pragma unroll
        for (int tt = 0; tt < TT; ++tt) {
            float4 xv = *(const float4*)(xs + tt * C_DIM + c0);
            #pragma unroll
            for (int k = 0; k < 4; ++k)
                h[k][tt] += xv.x * wv[0][k] + xv.y * wv[1][k] + xv.z * wv[2][k] + xv.w * wv[3][k];
        }
    }
    #pragma unroll
    for (int k = 0; k < 4; ++k)
        #pragma unroll
        for (int tt = 0; tt < TT; ++tt) {
            float v = h[k][tt];
            h[k][tt] = 0.5f * v * (1.f + erff(v * 0.70710678118f));
        }

    const float* Wp_e = Wproj + (size_t)e * H_DIM * C_DIM;
    float yacc[TT];
    {
        float bp = bproj[(size_t)e * C_DIM + j];
        #pragma unroll
        for (int tt = 0; tt < TT; ++tt) yacc[tt] = bp;
    }
    #pragma unroll
    for (int k = 0; k < 4; ++k) {
        __syncthreads();
        #pragma unroll
        for (int tt = 0; tt < TT; ++tt) hs[tt * C_DIM + j] = h[k][tt];
        __syncthreads();
        for (int h0 = 0; h0 < 256; h0 += 4) {
            float wv[4];
            #pragma unroll
            for (int hi = 0; hi < 4; ++hi)
                wv[hi] = Wp_e[(size_t)(k * 256 + h0 + hi) * C_DIM + j];
            #pragma unroll
            for (int tt = 0; tt < TT; ++tt) {
                float4 hv = *(const float4*)(hs + tt * C_DIM + h0);
                yacc[tt] += hv.x * wv[0] + hv.y * wv[1] + hv.z * wv[2] + hv.w * wv[3];
            }
        }
    }

    __syncthreads();
    #pragma unroll
    for (int tt = 0; tt < TT; ++tt) hs[tt * C_DIM + j] = yacc[tt];
    __syncthreads();

    const float cc0 = cptr[0];
    const int wave = j >> 6, lane = j & 63;
    for (int q = 0; q < 4; ++q) {
        int tt = wave * 4 + q;
        if (tt >= nt) break;
        int tok = stok[tt];
        float s2 = 0.f, sxy = 0.f;
        #pragma unroll
        for (int m = 0; m < 4; ++m) {
            int ccol = lane + 64 * m;
            float yv = hs[tt * C_DIM + ccol];
            float rv = rfp[(size_t)tok * C_DIM + ccol];
            s2 += yv * yv; sxy += rv * yv;
        }
        #pragma unroll
        for (int off = 32; off; off >>= 1) {
            s2  += __shfl_down(s2, off);
            sxy += __shfl_down(sxy, off);
        }
        if (lane == 0) {
            float ref2 = ref2p[tok];
            float sf = 2.f / (1.f + cc0 * ref2);
            float vn = sqrtf(s2);
            float a = sqrtf(cc0 * sf * 0.5f);
            float alpha = (vn > 1e-20f)
                        ? (tanhf(a * vn) / (vn * sqrtf(cc0)))
                        : (a / sqrtf(cc0));
            float axy = alpha * sxy;
            float ay2 = alpha * alpha * s2;
            float A   = 1.f + 2.f * cc0 * axy + cc0 * ay2;
            float Bc  = (1.f - cc0 * ref2) * alpha;
            float den = 1.f + 2.f * cc0 * axy + cc0 * cc0 * ref2 * ay2;
            float wi  = swgt[tt] / den;
            scA[tt] = A * wi;
            scB[tt] = Bc * wi;
        }
    }
    __syncthreads();

    for (int tt = 0; tt < nt; ++tt) {
        int tok = stok[tt];
        float rv = rfp[(size_t)tok * C_DIM + j];
        float yv = hs[tt * C_DIM + j];
        atomicAdd(&out[(size_t)tok * C_DIM + j], scA[tt] * rv + scB[tt] * yv);
    }
}

extern "C" void kernel_launch(void* const* d_in, const int* in_sizes, int n_in,
                              void* d_out, int out_size, void* d_ws, size_t ws_size,
                              hipStream_t stream) {
    (void)in_sizes; (void)n_in; (void)out_size;
    const float* x     = (const float*)d_in[0];
    const float* rfp   = (const float*)d_in[1];
    const float* Wg    = (const float*)d_in[2];
    const float* bg    = (const float*)d_in[3];
    const float* ebias = (const float*)d_in[4];
    const float* Wfc   = (const float*)d_in[5];
    const float* bfc   = (const float*)d_in[6];
    const float* Wproj = (const float*)d_in[7];
    const float* bproj = (const float*)d_in[8];
    const float* cptr  = (const float*)d_in[9];

    float* out = (float*)d_out;                       // [n, C]
    float* rw  = out + (size_t)N_TOK * C_DIM;         // [n, E]

    constexpr size_t OFF_BTOK  = 128;
    constexpr size_t OFF_BWGT  = OFF_BTOK + (size_t)E_DIM * N_TOK * 4;
    constexpr size_t OFF_REF2  = OFF_BWGT + (size_t)E_DIM * N_TOK * 4;
    constexpr size_t OFF_CHO   = ((OFF_REF2 + (size_t)N_TOK * 4 + 255) / 256) * 256;
    constexpr size_t OFF_TBL   = OFF_CHO + (size_t)N_TOK * 16;
    constexpr size_t OFF_WFC   = OFF_TBL + 4096;
    constexpr size_t SZ_W      = (size_t)E_DIM * C_DIM * H_DIM * 2;  // 16 MB bf16 each
    constexpr size_t OFF_WPROJ = OFF_WFC + SZ_W;
    constexpr size_t OFF_PART  = OFF_WPROJ + SZ_W;
    constexpr size_t SZ_PART   = (size_t)4 * N_TOK * C_DIM * 4;      // 16 MB
    constexpr size_t WS_FULL   = OFF_PART + SZ_PART;

    char*  ws     = (char*)d_ws;
    int*   counts = (int*)ws;
    int*   btok   = (int*)(ws + OFF_BTOK);
    float* bwgt   = (float*)(ws + OFF_BWGT);
    float* ref2   = (float*)(ws + OFF_REF2);
    float4* cho   = (float4*)(ws + OFF_CHO);
    int*   tbl    = (int*)(ws + OFF_TBL);

    if (ws_size >= WS_FULL) {
        ushort_t* WfcF   = (ushort_t*)(ws + OFF_WFC);
        ushort_t* WprojF = (ushort_t*)(ws + OFF_WPROJ);
        float*    part   = (float*)(ws + OFF_PART);
        wtrans_kernel<<<E_DIM * 64, 256, 0, stream>>>(Wfc, Wproj, WfcF, WprojF);
        gate_kernel<<<N_TOK / 4, 256, 0, stream>>>(x, rfp, Wg, bg, ebias,
                                                   rw, btok, bwgt, ref2, cho);
        bucketize_kernel<<<G_DIM, 256, 0, stream>>>(cho, btok, bwgt, counts);
        finalize_kernel<<<1, 64, 0, stream>>>(counts, tbl);
        expert_mfma32p<<<TBL_MAX, 256, 0, stream>>>(x, rfp, WfcF, WprojF, bfc, bproj,
                                                    cptr, ref2, counts, btok, bwgt, tbl, part);
        combine_kernel<<<(N_TOK * C_DIM) / 1024, 256, 0, stream>>>(part, out);
    } else {
        hipMemsetAsync(out, 0, (size_t)N_TOK * C_DIM * sizeof(float), stream);
        gate_kernel<<<N_TOK / 4, 256, 0, stream>>>(x, rfp, Wg, bg, ebias,
                                                   rw, btok, bwgt, ref2, cho);
        bucketize_kernel<<<G_DIM, 256, 0, stream>>>(cho, btok, bwgt, counts);
        dim3 grid(E_DIM, N_TOK / TT);
        expert_kernel<<<grid, 256, 0, stream>>>(x, rfp, Wfc, bfc, Wproj, bproj,
                                                cptr, ref2, counts, btok, bwgt, out);
    }
}